// Round 5
// baseline (476.124 us; speedup 1.0000x reference)
//
#include <hip/hip_runtime.h>

// ---------------------------------------------------------------------------
// Fused attention: x@Wqkv^T -> RoPE -> masked softmax attention -> @Wproj^T+b
// B=2, N=2048, C=1024, H=16, D=64.  All MFMA compute in bf16, fp32 accum.
// ---------------------------------------------------------------------------

typedef __attribute__((ext_vector_type(8))) short          s16x8;
typedef __attribute__((ext_vector_type(8))) unsigned short u16x8;
typedef __attribute__((ext_vector_type(4))) unsigned short u16x4;
typedef __attribute__((ext_vector_type(4))) float          f32x4;

#define MFMA_BF16(a, b, c) __builtin_amdgcn_mfma_f32_16x16x32_bf16((a), (b), (c), 0, 0, 0)

// async global->LDS, 16B per lane (dest = wave-uniform base + lane*16)
#define GLD_TO_LDS(gp, lp) __builtin_amdgcn_global_load_lds(                  \
    (const __attribute__((address_space(1))) void*)(gp),                      \
    (__attribute__((address_space(3))) void*)(lp), 16, 0, 0)

__device__ __forceinline__ unsigned short f2bf(float f) {
    union { float f; unsigned int u; } v; v.f = f;
    unsigned int u = v.u;
    unsigned int r = u + 0x7FFFu + ((u >> 16) & 1u);   // round-to-nearest-even
    return (unsigned short)(r >> 16);
}

// ---------------------------------------------------------------------------
// prep: fp32->bf16 converts for x, w_qkv, w_proj + mask->float bias.
// Block ranges are exact multiples of 256 threads, so no intra-block branch
// divergence: [0,4096) x, [4096,7168) w_qkv, [7168,8192) w_proj, [8192,8208) mask.
// ---------------------------------------------------------------------------
__global__ __launch_bounds__(256) void prep(const float* __restrict__ x,
                                            const float* __restrict__ wqkv,
                                            const float* __restrict__ wproj,
                                            const int* __restrict__ m,
                                            unsigned short* __restrict__ xb,
                                            unsigned short* __restrict__ wqkvb,
                                            unsigned short* __restrict__ wprojb,
                                            float* __restrict__ fb) {
    int blk = blockIdx.x, tid = threadIdx.x;
    if (blk < 8192) {
        const float* src; unsigned short* dst; int i;
        if (blk < 4096)      { src = x;     dst = xb;     i = blk * 256 + tid; }
        else if (blk < 7168) { src = wqkv;  dst = wqkvb;  i = (blk - 4096) * 256 + tid; }
        else                 { src = wproj; dst = wprojb; i = (blk - 7168) * 256 + tid; }
        f32x4 v = ((const f32x4*)src)[i];
        u16x4 o;
        o[0] = f2bf(v[0]); o[1] = f2bf(v[1]); o[2] = f2bf(v[2]); o[3] = f2bf(v[3]);
        ((u16x4*)dst)[i] = o;
    } else {
        int i = (blk - 8192) * 256 + tid;
        fb[i] = (m[i] == 0) ? -1e5f : 0.0f;
    }
}

// ---------------------------------------------------------------------------
// QKV GEMM + fused RoPE + scatter.  C-tile = x[128 rows] @ w_qkv^T[128 cols].
// Each 128-col tile lies entirely in one of {q,k,v} and spans exactly 2 heads.
// RoPE pair (d, d^32) = acc[i][j^2] in the SAME lane -> applied in-register
// on fp32 accumulators.  q/k tiles write Q/K [B,H,N,D]; v tiles transpose via
// a 2-pass LDS bounce (reusing Al/Bl space) into Vt [B,H,D,N].
// ---------------------------------------------------------------------------
__global__ __launch_bounds__(256) void gemm_qkv_rope(const unsigned short* __restrict__ A,
                                                     const unsigned short* __restrict__ B,
                                                     unsigned short* __restrict__ Qm,
                                                     unsigned short* __restrict__ Km,
                                                     unsigned short* __restrict__ Vtm) {
    const int K = 1024;
    __shared__ unsigned short base[128 * 128];                 // 32 KB
    unsigned short (*Al)[64] = (unsigned short(*)[64])base;
    unsigned short (*Bl)[64] = (unsigned short(*)[64])(base + 128 * 64);
    const int tid  = threadIdx.x;
    const int lane = tid & 63;
    const int qd   = lane >> 4;
    const int cc   = lane & 15;
    const int wave = tid >> 6;
    const int wr   = wave >> 1, wc = wave & 1;
    const int m0   = blockIdx.y * 128, n0 = blockIdx.x * 128;

    f32x4 acc[4][4];
#pragma unroll
    for (int i = 0; i < 4; i++)
#pragma unroll
        for (int j = 0; j < 4; j++) acc[i][j] = (f32x4){0.f, 0.f, 0.f, 0.f};

    for (int k0 = 0; k0 < K; k0 += 64) {
#pragma unroll
        for (int t = 0; t < 4; t++) {
            int idx = t * 256 + tid;
            int row = idx >> 3, sg = (idx & 7) ^ (row & 7);
            GLD_TO_LDS(A + (size_t)(m0 + row) * K + k0 + sg * 8, base + idx * 8);
            GLD_TO_LDS(B + (size_t)(n0 + row) * K + k0 + sg * 8, base + 8192 + idx * 8);
        }
        __syncthreads();
#pragma unroll
        for (int ks = 0; ks < 64; ks += 32) {
            const int s4 = ks >> 3;
            s16x8 af[4], bf[4];
#pragma unroll
            for (int i = 0; i < 4; i++) {
                int r = wr * 64 + i * 16 + cc;
                af[i] = *(const s16x8*)&Al[r][((s4 + qd) ^ (r & 7)) * 8];
            }
#pragma unroll
            for (int j = 0; j < 4; j++) {
                int r = wc * 64 + j * 16 + cc;
                bf[j] = *(const s16x8*)&Bl[r][((s4 + qd) ^ (r & 7)) * 8];
            }
#pragma unroll
            for (int i = 0; i < 4; i++)
#pragma unroll
                for (int j = 0; j < 4; j++)
                    acc[i][j] = MFMA_BF16(af[i], bf[j], acc[i][j]);
        }
        __syncthreads();
    }

    const int sec = n0 >> 10;            // 0=q, 1=k, 2=v
    const int b   = m0 >> 11;
    if (sec < 2) {
        // RoPE on fp32 acc, write bf16 to Q/K [b][h][n][d]
        unsigned short* dst = sec ? Km : Qm;
        const int h = ((n0 & 1023) >> 6) + wc;
        const float if0 = exp2f(-0.34375f * (float)cc);          // d&31 = cc   (j even)
        const float if1 = exp2f(-0.34375f * (float)(16 + cc));   // d&31 = 16+cc (j odd)
        const size_t hb = (size_t)(b * 16 + h) * 2048;
#pragma unroll
        for (int i = 0; i < 4; i++)
#pragma unroll
            for (int r = 0; r < 4; r++) {
                int n = (m0 + wr * 64 + i * 16 + qd * 4 + r) & 2047;
                float fn = (float)n;
                float t0 = fn * if0, t1 = fn * if1;
                float c0 = cosf(t0), s0 = sinf(t0);
                float c1 = cosf(t1), s1 = sinf(t1);
                size_t rp = (hb + n) * 64;
#pragma unroll
                for (int j = 0; j < 4; j++) {
                    float cv = (j & 1) ? c1 : c0;
                    float sv = (j & 1) ? s1 : s0;
                    float pr = acc[i][j ^ 2][r] * sv;             // rotate_half partner
                    float v  = (j & 2) ? fmaf(acc[i][j][r], cv, pr)
                                       : fmaf(acc[i][j][r], cv, -pr);
                    dst[rp + j * 16 + cc] = f2bf(v);
                }
            }
    } else {
        // V: 2-pass transpose through LDS -> Vt [b][h][d][n]
        unsigned short (*T)[72] = (unsigned short(*)[72])base;   // 128x72 = 18.4 KB
        const int h0 = (n0 & 1023) >> 6;
        const int dd = tid >> 2, ns = tid & 3;
#pragma unroll
        for (int p = 0; p < 2; p++) {
            __syncthreads();
            if (wc == p) {
#pragma unroll
                for (int i = 0; i < 4; i++)
#pragma unroll
                    for (int j = 0; j < 4; j++)
#pragma unroll
                        for (int r = 0; r < 4; r++)
                            T[wr * 64 + i * 16 + qd * 4 + r][j * 16 + cc] =
                                f2bf(acc[i][j][r]);
            }
            __syncthreads();
            size_t vb = ((size_t)(b * 16 + h0 + p) * 64 + dd) * 2048 + (m0 & 2047);
#pragma unroll
            for (int c = 0; c < 4; c++) {
                int nf = ns * 32 + c * 8;
                u16x8 ov;
#pragma unroll
                for (int t = 0; t < 8; t++) ov[t] = T[nf + t][dd];
                *(u16x8*)&Vtm[vb + nf] = ov;
            }
        }
    }
}

// ---------------------------------------------------------------------------
// Flash attention v5: K dbuf-DMA staged, V direct from global (L2-resident),
// S^T orientation, softmax-lite (no running max), l via MFMA-with-ones.
// Block = (128-q-tile, h, b); 4 waves x 32 q-rows; K-tiles of 64.
// ---------------------------------------------------------------------------
__global__ __launch_bounds__(256, 2) void flash_attn(const unsigned short* __restrict__ Q,
                                                     const unsigned short* __restrict__ Kg,
                                                     const unsigned short* __restrict__ Vt,
                                                     const float* __restrict__ fb,
                                                     unsigned short* __restrict__ Og) {
    const int N = 2048, H = 16, D = 64;
    const float SCL = 0.18033688f;             // 0.125 * log2(e)
    __shared__ unsigned short Kl0[64][64], Kl1[64][64];   // [key][d] swizzled
    __shared__ unsigned short Pl[4][32][76];   // [wave][query][key], stride 76
    const int tid  = threadIdx.x;
    const int lane = tid & 63;
    const int wave = tid >> 6;
    const int qd   = lane >> 4;
    const int cc   = lane & 15;
    const int qt = blockIdx.x, h = blockIdx.y, b = blockIdx.z;
    const int q0 = qt * 128;
    const size_t bh = (size_t)b * H + h;

    // Q B-frags: B[n=q=lane&15][k=d=quad*8+j]
    s16x8 qf[2][2];
#pragma unroll
    for (int fr = 0; fr < 2; fr++) {
        const unsigned short* Qb = Q + (bh * N + q0 + wave * 32 + fr * 16 + cc) * D;
        qf[fr][0] = *(const s16x8*)(Qb + qd * 8);
        qf[fr][1] = *(const s16x8*)(Qb + 32 + qd * 8);
    }

    s16x8 ones;                                // bf16 1.0 for l = P @ 1
#pragma unroll
    for (int j = 0; j < 8; j++) ones[j] = (short)0x3F80;

    f32x4 o[2][4], lacc[2];
#pragma unroll
    for (int fr = 0; fr < 2; fr++) {
        lacc[fr] = (f32x4){0.f, 0.f, 0.f, 0.f};
#pragma unroll
        for (int db = 0; db < 4; db++) o[fr][db] = (f32x4){0.f, 0.f, 0.f, 0.f};
    }

    const unsigned short* Kbase = Kg + bh * N * D;
    const unsigned short* Vbase = Vt + bh * D * N;
    const float* fbase = fb + (size_t)b * N;
    const int row_s = tid >> 3, sg_s = (tid & 7) ^ ((tid >> 3) & 7);
    const int row_s2 = (tid + 256) >> 3, sg_s2 = (tid & 7) ^ (((tid + 256) >> 3) & 7);

    auto issueK = [&](int k0, unsigned short* Kb) {
        GLD_TO_LDS(Kbase + (size_t)(k0 + row_s) * D + sg_s * 8,   Kb + tid * 8);
        GLD_TO_LDS(Kbase + (size_t)(k0 + row_s2) * D + sg_s2 * 8, Kb + (tid + 256) * 8);
    };

    auto body = [&](int k0, const unsigned short (*Kb)[64], int nk0, unsigned short* KbN) {
        // V frags for THIS tile, straight from global — issued first, consumed
        // after ~800 cyc of S^T+exp work (covers L2 latency)
        s16x8 vf[2][4];
#pragma unroll
        for (int ks = 0; ks < 2; ks++)
#pragma unroll
            for (int db = 0; db < 4; db++)
                vf[ks][db] = *(const s16x8*)(Vbase + (size_t)(db * 16 + cc) * N
                                             + k0 + ks * 32 + qd * 8);
        f32x4 fbv[4];
#pragma unroll
        for (int sub = 0; sub < 4; sub++)
            fbv[sub] = *(const f32x4*)(fbase + k0 + sub * 16 + qd * 4);
        // prefetch next K tile via DMA
        if (nk0 < N) issueK(nk0, KbN);

        // S^T = K Q^T, softmax-lite, pack pairs -> Pl
#pragma unroll
        for (int sub = 0; sub < 4; sub++) {
            int kr = sub * 16 + cc;
            s16x8 kf0 = *(const s16x8*)&Kb[kr][((0 + qd) ^ (kr & 7)) * 8];
            s16x8 kf1 = *(const s16x8*)&Kb[kr][((4 + qd) ^ (kr & 7)) * 8];
#pragma unroll
            for (int fr = 0; fr < 2; fr++) {
                f32x4 s = (f32x4){0.f, 0.f, 0.f, 0.f};
                s = MFMA_BF16(kf0, qf[fr][0], s);
                s = MFMA_BF16(kf1, qf[fr][1], s);
                float p0 = exp2f(fmaf(s[0], SCL, fbv[sub][0]));
                float p1 = exp2f(fmaf(s[1], SCL, fbv[sub][1]));
                float p2 = exp2f(fmaf(s[2], SCL, fbv[sub][2]));
                float p3 = exp2f(fmaf(s[3], SCL, fbv[sub][3]));
                unsigned int d0 = __builtin_amdgcn_perm(
                    __builtin_bit_cast(unsigned int, p1),
                    __builtin_bit_cast(unsigned int, p0), 0x07060302u);
                unsigned int d1 = __builtin_amdgcn_perm(
                    __builtin_bit_cast(unsigned int, p3),
                    __builtin_bit_cast(unsigned int, p2), 0x07060302u);
                unsigned long long w = ((unsigned long long)d1 << 32) | d0;
                *(unsigned long long*)&Pl[wave][fr * 16 + cc][sub * 16 + qd * 4] = w;
            }
        }

        // O += P V ; l += P @ 1
#pragma unroll
        for (int ks = 0; ks < 2; ks++)
#pragma unroll
            for (int fr = 0; fr < 2; fr++) {
                s16x8 pf = *(const s16x8*)&Pl[wave][fr * 16 + cc][ks * 32 + qd * 8];
                lacc[fr] = MFMA_BF16(pf, ones, lacc[fr]);
#pragma unroll
                for (int db = 0; db < 4; db++)
                    o[fr][db] = MFMA_BF16(pf, vf[ks][db], o[fr][db]);
            }
    };

    issueK(0, &Kl0[0][0]);
    __syncthreads();
    for (int it = 0; it < 32; it += 2) {
        int k0 = it * 64;
        body(k0, Kl0, k0 + 64, &Kl1[0][0]);
        __syncthreads();
        body(k0 + 64, Kl1, k0 + 128, &Kl0[0][0]);
        __syncthreads();
    }

    // epilogue: lacc rows == o rows (query = fr*16 + qd*4 + r)
#pragma unroll
    for (int fr = 0; fr < 2; fr++) {
        float linv[4];
#pragma unroll
        for (int r = 0; r < 4; r++) linv[r] = 1.0f / lacc[fr][r];
#pragma unroll
        for (int db = 0; db < 4; db++)
#pragma unroll
            for (int r = 0; r < 4; r++) {
                int n = q0 + wave * 32 + fr * 16 + qd * 4 + r;
                Og[((size_t)b * N + n) * 1024 + h * 64 + db * 16 + cc] =
                    f2bf(o[fr][db][r] * linv[r]);
            }
    }
}

// ---------------------------------------------------------------------------
// Projection GEMM: out[4096,1024] = attno[4096,1024] @ w_proj^T + bias, fp32.
// 128x64 tile (vs 128x128) -> 512 blocks = 2 blocks/CU (was 1).
// ---------------------------------------------------------------------------
__global__ __launch_bounds__(256) void gemm_proj(const unsigned short* __restrict__ A,
                                                 const unsigned short* __restrict__ B,
                                                 float* __restrict__ C,
                                                 const float* __restrict__ bias) {
    const int NN = 1024, K = 1024;
    __shared__ unsigned short Al[128][64];
    __shared__ unsigned short Bl[64][64];
    const int tid  = threadIdx.x;
    const int lane = tid & 63;
    const int qd   = lane >> 4;
    const int cc   = lane & 15;
    const int wave = tid >> 6;
    const int wr   = wave >> 1, wc = wave & 1;
    const int m0   = blockIdx.y * 128, n0 = blockIdx.x * 64;
    unsigned short* Alf = &Al[0][0];
    unsigned short* Blf = &Bl[0][0];

    f32x4 acc[4][2];
#pragma unroll
    for (int i = 0; i < 4; i++)
#pragma unroll
        for (int j = 0; j < 2; j++) acc[i][j] = (f32x4){0.f, 0.f, 0.f, 0.f};

    for (int k0 = 0; k0 < K; k0 += 64) {
#pragma unroll
        for (int t = 0; t < 4; t++) {
            int idx = t * 256 + tid;
            int row = idx >> 3, sg = (idx & 7) ^ (row & 7);
            GLD_TO_LDS(A + (size_t)(m0 + row) * K + k0 + sg * 8, Alf + idx * 8);
        }
#pragma unroll
        for (int t = 0; t < 2; t++) {
            int idx = t * 256 + tid;
            int row = idx >> 3, sg = (idx & 7) ^ (row & 7);
            GLD_TO_LDS(B + (size_t)(n0 + row) * K + k0 + sg * 8, Blf + idx * 8);
        }
        __syncthreads();
#pragma unroll
        for (int ks = 0; ks < 64; ks += 32) {
            const int s4 = ks >> 3;
            s16x8 af[4], bf[2];
#pragma unroll
            for (int i = 0; i < 4; i++) {
                int r = wr * 64 + i * 16 + cc;
                af[i] = *(const s16x8*)&Al[r][((s4 + qd) ^ (r & 7)) * 8];
            }
#pragma unroll
            for (int j = 0; j < 2; j++) {
                int r = wc * 32 + j * 16 + cc;
                bf[j] = *(const s16x8*)&Bl[r][((s4 + qd) ^ (r & 7)) * 8];
            }
#pragma unroll
            for (int i = 0; i < 4; i++)
#pragma unroll
                for (int j = 0; j < 2; j++)
                    acc[i][j] = MFMA_BF16(af[i], bf[j], acc[i][j]);
        }
        __syncthreads();
    }
#pragma unroll
    for (int i = 0; i < 4; i++)
#pragma unroll
        for (int j = 0; j < 2; j++)
#pragma unroll
            for (int r = 0; r < 4; r++) {
                int row = m0 + wr * 64 + i * 16 + qd * 4 + r;
                int col = n0 + wc * 32 + j * 16 + cc;
                C[(size_t)row * NN + col] = acc[i][j][r] + bias[col];
            }
}

// ---------------------------------------------------------------------------
extern "C" void kernel_launch(void* const* d_in, const int* in_sizes, int n_in,
                              void* d_out, int out_size, void* d_ws, size_t ws_size,
                              hipStream_t stream) {
    const float* x      = (const float*)d_in[0];
    const float* w_qkv  = (const float*)d_in[1];
    const float* w_proj = (const float*)d_in[2];
    const float* b_proj = (const float*)d_in[3];
    const int*   mask   = (const int*)d_in[4];
    float* out = (float*)d_out;

    // workspace layout (bf16 elements), ~48 MB
    unsigned short* ws     = (unsigned short*)d_ws;
    unsigned short* xb     = ws;                                  // 4096*1024
    unsigned short* wqkvb  = xb     + (size_t)4096 * 1024;        // 3072*1024
    unsigned short* wprojb = wqkvb  + (size_t)3072 * 1024;        // 1024*1024
    unsigned short* Qm     = wprojb + (size_t)1024 * 1024;        // 32*2048*64
    unsigned short* Km     = Qm     + (size_t)32 * 2048 * 64;
    unsigned short* Vtm    = Km     + (size_t)32 * 2048 * 64;
    unsigned short* attno  = Vtm    + (size_t)32 * 2048 * 64;     // 4096*1024
    float*          fbias  = (float*)(attno + (size_t)4096 * 1024); // 2*2048 f32

    // converts + mask bias, one launch
    prep<<<8208, 256, 0, stream>>>(x, w_qkv, w_proj, mask, xb, wqkvb, wprojb, fbias);
    // QKV GEMM with fused RoPE + scatter to Q/K [B,H,N,D] and Vt [B,H,D,N]
    gemm_qkv_rope<<<dim3(24, 32), 256, 0, stream>>>(xb, wqkvb, Qm, Km, Vtm);
    // attention
    flash_attn<<<dim3(16, 16, 2), 256, 0, stream>>>(Qm, Km, Vtm, fbias, attno);
    // out = attn_out @ w_proj^T + b_proj
    gemm_proj<<<dim3(16, 32), 256, 0, stream>>>(attno, wprojb, out, b_proj);
}

// Round 6
// 209.459 us; speedup vs baseline: 2.2731x; 2.2731x over previous
//
#include <hip/hip_runtime.h>

// ---------------------------------------------------------------------------
// Fused attention: x@Wqkv^T -> RoPE -> masked softmax attention -> @Wproj^T+b
// B=2, N=2048, C=1024, H=16, D=64.  All MFMA compute in bf16, fp32 accum.
//
// LESSON (R5): do NOT fuse RoPE-scatter into the GEMM epilogue with scalar
// 2B global stores — partial-sector writes caused ~16x HBM write
// amplification (WRITE_SIZE 1.03 GB vs 32 MB payload) and a 6x kernel
// regression.  Dense u16x8 stores from a dedicated scatter kernel are fast.
// ---------------------------------------------------------------------------

typedef __attribute__((ext_vector_type(8))) short          s16x8;
typedef __attribute__((ext_vector_type(8))) unsigned short u16x8;
typedef __attribute__((ext_vector_type(4))) unsigned short u16x4;
typedef __attribute__((ext_vector_type(4))) float          f32x4;

#define MFMA_BF16(a, b, c) __builtin_amdgcn_mfma_f32_16x16x32_bf16((a), (b), (c), 0, 0, 0)

// async global->LDS, 16B per lane (dest = wave-uniform base + lane*16)
#define GLD_TO_LDS(gp, lp) __builtin_amdgcn_global_load_lds(                  \
    (const __attribute__((address_space(1))) void*)(gp),                      \
    (__attribute__((address_space(3))) void*)(lp), 16, 0, 0)

__device__ __forceinline__ unsigned short f2bf(float f) {
    union { float f; unsigned int u; } v; v.f = f;
    unsigned int u = v.u;
    unsigned int r = u + 0x7FFFu + ((u >> 16) & 1u);   // round-to-nearest-even
    return (unsigned short)(r >> 16);
}
__device__ __forceinline__ float bf2f(unsigned short h) {
    union { unsigned int u; float f; } v; v.u = ((unsigned int)h) << 16;
    return v.f;
}

// ---------------------------------------------------------------------------
// prep: fp32->bf16 converts for x, w_qkv, w_proj + mask->float bias.
// Block ranges are exact multiples of 256 threads:
// [0,4096) x, [4096,7168) w_qkv, [7168,8192) w_proj, [8192,8208) mask.
// ---------------------------------------------------------------------------
__global__ __launch_bounds__(256) void prep(const float* __restrict__ x,
                                            const float* __restrict__ wqkv,
                                            const float* __restrict__ wproj,
                                            const int* __restrict__ m,
                                            unsigned short* __restrict__ xb,
                                            unsigned short* __restrict__ wqkvb,
                                            unsigned short* __restrict__ wprojb,
                                            float* __restrict__ fb) {
    int blk = blockIdx.x, tid = threadIdx.x;
    if (blk < 8192) {
        const float* src; unsigned short* dst; int i;
        if (blk < 4096)      { src = x;     dst = xb;     i = blk * 256 + tid; }
        else if (blk < 7168) { src = wqkv;  dst = wqkvb;  i = (blk - 4096) * 256 + tid; }
        else                 { src = wproj; dst = wprojb; i = (blk - 7168) * 256 + tid; }
        f32x4 v = ((const f32x4*)src)[i];
        u16x4 o;
        o[0] = f2bf(v[0]); o[1] = f2bf(v[1]); o[2] = f2bf(v[2]); o[3] = f2bf(v[3]);
        ((u16x4*)dst)[i] = o;
    } else {
        int i = (blk - 8192) * 256 + tid;
        fb[i] = (m[i] == 0) ? -1e5f : 0.0f;
    }
}

// ---------------------------------------------------------------------------
// bf16 GEMM, C[M,N] = A[M,K] * B[N,K]^T, bf16 out.  128x128 tile, BK=64,
// 256 threads = 4 waves in 2x2, each wave 64x64 via 4x4 frags of 16x16x32.
// Staging via global_load_lds(16B) with XOR seg-swizzle (seg ^= row&7).
// ---------------------------------------------------------------------------
__global__ __launch_bounds__(256) void gemm_bt(const unsigned short* __restrict__ A,
                                               const unsigned short* __restrict__ B,
                                               unsigned short* __restrict__ C,
                                               int M, int N, int K) {
    __shared__ unsigned short Al[128][64];
    __shared__ unsigned short Bl[128][64];
    const int tid  = threadIdx.x;
    const int lane = tid & 63;
    const int qd   = lane >> 4;     // quad 0..3
    const int cc   = lane & 15;
    const int wave = tid >> 6;
    const int wr   = wave >> 1, wc = wave & 1;
    const int m0   = blockIdx.y * 128, n0 = blockIdx.x * 128;
    unsigned short* Alf = &Al[0][0];
    unsigned short* Blf = &Bl[0][0];

    f32x4 acc[4][4];
#pragma unroll
    for (int i = 0; i < 4; i++)
#pragma unroll
        for (int j = 0; j < 4; j++) acc[i][j] = (f32x4){0.f, 0.f, 0.f, 0.f};

    for (int k0 = 0; k0 < K; k0 += 64) {
#pragma unroll
        for (int t = 0; t < 4; t++) {
            int idx = t * 256 + tid;                 // 0..1023
            int row = idx >> 3, sg = (idx & 7) ^ (row & 7);
            GLD_TO_LDS(A + (size_t)(m0 + row) * K + k0 + sg * 8, Alf + idx * 8);
            GLD_TO_LDS(B + (size_t)(n0 + row) * K + k0 + sg * 8, Blf + idx * 8);
        }
        __syncthreads();
#pragma unroll
        for (int ks = 0; ks < 64; ks += 32) {
            const int s4 = ks >> 3;                  // 0 or 4
            s16x8 af[4], bf[4];
#pragma unroll
            for (int i = 0; i < 4; i++) {
                int r = wr * 64 + i * 16 + cc;
                af[i] = *(const s16x8*)&Al[r][((s4 + qd) ^ (r & 7)) * 8];
            }
#pragma unroll
            for (int j = 0; j < 4; j++) {
                int r = wc * 64 + j * 16 + cc;
                bf[j] = *(const s16x8*)&Bl[r][((s4 + qd) ^ (r & 7)) * 8];
            }
#pragma unroll
            for (int i = 0; i < 4; i++)
#pragma unroll
                for (int j = 0; j < 4; j++)
                    acc[i][j] = MFMA_BF16(af[i], bf[j], acc[i][j]);
        }
        __syncthreads();
    }
    // epilogue: C/D layout col=lane&15, row=quad*4+reg
#pragma unroll
    for (int i = 0; i < 4; i++)
#pragma unroll
        for (int j = 0; j < 4; j++)
#pragma unroll
            for (int r = 0; r < 4; r++) {
                int row = m0 + wr * 64 + i * 16 + qd * 4 + r;
                int col = n0 + wc * 64 + j * 16 + cc;
                C[(size_t)row * N + col] = f2bf(acc[i][j][r]);
            }
}

// ---------------------------------------------------------------------------
// RoPE + scatter: qkv[4096,3072] bf16 -> Q[B,H,N,D], K[B,H,N,D] (RoPE'd),
// V transposed -> Vt[B,H,D,N].  One block per (b,h,64-row tile).
// All global stores are dense u16x8 (16B) — see R5 lesson above.
// ---------------------------------------------------------------------------
__global__ __launch_bounds__(256) void rope_scatter(const unsigned short* __restrict__ qkv,
                                                    unsigned short* __restrict__ Q,
                                                    unsigned short* __restrict__ Kg,
                                                    unsigned short* __restrict__ Vt) {
    const int N = 2048, H = 16, D = 64, C3 = 3072;
    __shared__ unsigned short vl[64][65];   // +1 pad for transpose reads
    const int nt = blockIdx.x, h = blockIdx.y, b = blockIdx.z;
    const int n0 = nt * 64;
    const int tid = threadIdx.x;
    const size_t bh = (size_t)b * H + h;
#pragma unroll
    for (int it = 0; it < 2; it++) {
        int idx = tid + it * 256;           // 0..511
        int row = idx >> 3, seg = idx & 7;
        int d0 = seg * 8;
        int n = n0 + row;
        size_t rb = ((size_t)b * N + n) * C3;
        u16x8 qv = *(const u16x8*)&qkv[rb + h * 64 + d0];
        u16x8 qp = *(const u16x8*)&qkv[rb + h * 64 + (d0 ^ 32)];
        u16x8 kv = *(const u16x8*)&qkv[rb + 1024 + h * 64 + d0];
        u16x8 kp = *(const u16x8*)&qkv[rb + 1024 + h * 64 + (d0 ^ 32)];
        u16x8 vv = *(const u16x8*)&qkv[rb + 2048 + h * 64 + d0];
        u16x8 qo, ko;
        float sgn = (d0 < 32) ? -1.0f : 1.0f;   // rotate_half sign
#pragma unroll
        for (int j = 0; j < 8; j++) {
            int jj = (d0 & 31) + j;                              // freq index
            float th = (float)n * exp2f(-0.34375f * (float)jj);  // 2048^(-jj/32)
            float cth = cosf(th), sth = sinf(th);
            qo[j] = f2bf(bf2f(qv[j]) * cth + sgn * bf2f(qp[j]) * sth);
            ko[j] = f2bf(bf2f(kv[j]) * cth + sgn * bf2f(kp[j]) * sth);
            vl[row][d0 + j] = vv[j];
        }
        *(u16x8*)&Q[(bh * N + n) * D + d0]  = qo;
        *(u16x8*)&Kg[(bh * N + n) * D + d0] = ko;
    }
    __syncthreads();
    // transposed V write: Vt[b,h,d,n]
#pragma unroll
    for (int it = 0; it < 2; it++) {
        int idx = tid + it * 256;
        int drow = idx >> 3, nseg = idx & 7;
        u16x8 ov;
#pragma unroll
        for (int j = 0; j < 8; j++) ov[j] = vl[nseg * 8 + j][drow];
        *(u16x8*)&Vt[(bh * D + drow) * N + n0 + nseg * 8] = ov;
    }
}

// ---------------------------------------------------------------------------
// Flash attention (R4, measured 71 us): double-buffered DMA staging of K AND
// V, S^T orientation, softmax-lite (no running max), l via MFMA-with-ones.
// Block = (128-q-tile, h, b); 4 waves x 32 q-rows; K-tiles of 64.
// ---------------------------------------------------------------------------
__global__ __launch_bounds__(256, 2) void flash_attn(const unsigned short* __restrict__ Q,
                                                     const unsigned short* __restrict__ Kg,
                                                     const unsigned short* __restrict__ Vt,
                                                     const float* __restrict__ fb,
                                                     unsigned short* __restrict__ Og) {
    const int N = 2048, H = 16, D = 64;
    const float SCL = 0.18033688f;             // 0.125 * log2(e)
    __shared__ unsigned short Kl0[64][64], Kl1[64][64];   // [key][d] swizzled
    __shared__ unsigned short Vl0[64][64], Vl1[64][64];   // [d][key] swizzled
    __shared__ unsigned short Pl[4][32][76];   // [wave][query][key], stride 76
    const int tid  = threadIdx.x;
    const int lane = tid & 63;
    const int wave = tid >> 6;
    const int qd   = lane >> 4;
    const int cc   = lane & 15;
    const int qt = blockIdx.x, h = blockIdx.y, b = blockIdx.z;
    const int q0 = qt * 128;
    const size_t bh = (size_t)b * H + h;

    // Q B-frags: B[n=q=lane&15][k=d=quad*8+j]
    s16x8 qf[2][2];
#pragma unroll
    for (int fr = 0; fr < 2; fr++) {
        const unsigned short* Qb = Q + (bh * N + q0 + wave * 32 + fr * 16 + cc) * D;
        qf[fr][0] = *(const s16x8*)(Qb + qd * 8);
        qf[fr][1] = *(const s16x8*)(Qb + 32 + qd * 8);
    }

    // constant ones B-fragment (bf16 1.0 = 0x3F80) for l = P @ 1
    s16x8 ones;
#pragma unroll
    for (int j = 0; j < 8; j++) ones[j] = (short)0x3F80;

    f32x4 o[2][4], lacc[2];
#pragma unroll
    for (int fr = 0; fr < 2; fr++) {
        lacc[fr] = (f32x4){0.f, 0.f, 0.f, 0.f};
#pragma unroll
        for (int db = 0; db < 4; db++) o[fr][db] = (f32x4){0.f, 0.f, 0.f, 0.f};
    }

    const unsigned short* Kbase = Kg + bh * N * D;
    const unsigned short* Vbase = Vt + bh * D * N;
    const float* fbase = fb + (size_t)b * N;
    const int row_s = tid >> 3, sg_s = (tid & 7) ^ ((tid >> 3) & 7);
    const int row_s2 = (tid + 256) >> 3, sg_s2 = (tid & 7) ^ (((tid + 256) >> 3) & 7);

    auto issue = [&](int k0, unsigned short* Kb, unsigned short* Vb) {
        GLD_TO_LDS(Kbase + (size_t)(k0 + row_s) * D + sg_s * 8,  Kb + tid * 8);
        GLD_TO_LDS(Vbase + (size_t)row_s * N + k0 + sg_s * 8,    Vb + tid * 8);
        GLD_TO_LDS(Kbase + (size_t)(k0 + row_s2) * D + sg_s2 * 8, Kb + (tid + 256) * 8);
        GLD_TO_LDS(Vbase + (size_t)row_s2 * N + k0 + sg_s2 * 8,   Vb + (tid + 256) * 8);
    };

    auto compute = [&](int k0, const unsigned short (*Kb)[64], const unsigned short (*Vb)[64]) {
        f32x4 fbv[4];
#pragma unroll
        for (int sub = 0; sub < 4; sub++)
            fbv[sub] = *(const f32x4*)(fbase + k0 + sub * 16 + qd * 4);

        // S^T = K Q^T, softmax-lite, pack pairs -> Pl
#pragma unroll
        for (int sub = 0; sub < 4; sub++) {
            int kr = sub * 16 + cc;
            s16x8 kf0 = *(const s16x8*)&Kb[kr][((0 + qd) ^ (kr & 7)) * 8];
            s16x8 kf1 = *(const s16x8*)&Kb[kr][((4 + qd) ^ (kr & 7)) * 8];
#pragma unroll
            for (int fr = 0; fr < 2; fr++) {
                f32x4 s = (f32x4){0.f, 0.f, 0.f, 0.f};
                s = MFMA_BF16(kf0, qf[fr][0], s);
                s = MFMA_BF16(kf1, qf[fr][1], s);
                float p0 = exp2f(fmaf(s[0], SCL, fbv[sub][0]));
                float p1 = exp2f(fmaf(s[1], SCL, fbv[sub][1]));
                float p2 = exp2f(fmaf(s[2], SCL, fbv[sub][2]));
                float p3 = exp2f(fmaf(s[3], SCL, fbv[sub][3]));
                unsigned int d0 = __builtin_amdgcn_perm(
                    __builtin_bit_cast(unsigned int, p1),
                    __builtin_bit_cast(unsigned int, p0), 0x07060302u);
                unsigned int d1 = __builtin_amdgcn_perm(
                    __builtin_bit_cast(unsigned int, p3),
                    __builtin_bit_cast(unsigned int, p2), 0x07060302u);
                unsigned long long w = ((unsigned long long)d1 << 32) | d0;
                *(unsigned long long*)&Pl[wave][fr * 16 + cc][sub * 16 + qd * 4] = w;
            }
        }

        // O += P V ; l += P @ 1  (A-frag P[m=q][k=key] contiguous reads)
#pragma unroll
        for (int ks = 0; ks < 2; ks++) {
            s16x8 vfl[4];
#pragma unroll
            for (int db = 0; db < 4; db++) {
                int vr = db * 16 + cc;
                vfl[db] = *(const s16x8*)&Vb[vr][((ks * 4 + qd) ^ (vr & 7)) * 8];
            }
#pragma unroll
            for (int fr = 0; fr < 2; fr++) {
                s16x8 pf = *(const s16x8*)&Pl[wave][fr * 16 + cc][ks * 32 + qd * 8];
                lacc[fr] = MFMA_BF16(pf, ones, lacc[fr]);
#pragma unroll
                for (int db = 0; db < 4; db++)
                    o[fr][db] = MFMA_BF16(pf, vfl[db], o[fr][db]);
            }
        }
    };

    issue(0, &Kl0[0][0], &Vl0[0][0]);
    __syncthreads();
    for (int it = 0; it < 32; it += 2) {
        int k0 = it * 64;
        if (it + 1 < 32) issue(k0 + 64, &Kl1[0][0], &Vl1[0][0]);
        compute(k0, Kl0, Vl0);
        __syncthreads();
        if (it + 2 < 32) issue(k0 + 128, &Kl0[0][0], &Vl0[0][0]);
        compute(k0 + 64, Kl1, Vl1);
        __syncthreads();
    }

    // epilogue: lacc rows == o rows (query = fr*16 + qd*4 + r)
#pragma unroll
    for (int fr = 0; fr < 2; fr++) {
        float linv[4];
#pragma unroll
        for (int r = 0; r < 4; r++) linv[r] = 1.0f / lacc[fr][r];
#pragma unroll
        for (int db = 0; db < 4; db++)
#pragma unroll
            for (int r = 0; r < 4; r++) {
                int n = q0 + wave * 32 + fr * 16 + qd * 4 + r;
                Og[((size_t)b * N + n) * 1024 + h * 64 + db * 16 + cc] =
                    f2bf(o[fr][db][r] * linv[r]);
            }
    }
}

// ---------------------------------------------------------------------------
// Projection GEMM: out[4096,1024] = attno[4096,1024] @ w_proj^T + bias, fp32.
// 128x64 tile -> 512 blocks = 2 blocks/CU.
// ---------------------------------------------------------------------------
__global__ __launch_bounds__(256) void gemm_proj(const unsigned short* __restrict__ A,
                                                 const unsigned short* __restrict__ B,
                                                 float* __restrict__ C,
                                                 const float* __restrict__ bias) {
    const int NN = 1024, K = 1024;
    __shared__ unsigned short Al[128][64];
    __shared__ unsigned short Bl[64][64];
    const int tid  = threadIdx.x;
    const int lane = tid & 63;
    const int qd   = lane >> 4;
    const int cc   = lane & 15;
    const int wave = tid >> 6;
    const int wr   = wave >> 1, wc = wave & 1;
    const int m0   = blockIdx.y * 128, n0 = blockIdx.x * 64;
    unsigned short* Alf = &Al[0][0];
    unsigned short* Blf = &Bl[0][0];

    f32x4 acc[4][2];
#pragma unroll
    for (int i = 0; i < 4; i++)
#pragma unroll
        for (int j = 0; j < 2; j++) acc[i][j] = (f32x4){0.f, 0.f, 0.f, 0.f};

    for (int k0 = 0; k0 < K; k0 += 64) {
#pragma unroll
        for (int t = 0; t < 4; t++) {
            int idx = t * 256 + tid;
            int row = idx >> 3, sg = (idx & 7) ^ (row & 7);
            GLD_TO_LDS(A + (size_t)(m0 + row) * K + k0 + sg * 8, Alf + idx * 8);
        }
#pragma unroll
        for (int t = 0; t < 2; t++) {
            int idx = t * 256 + tid;
            int row = idx >> 3, sg = (idx & 7) ^ (row & 7);
            GLD_TO_LDS(B + (size_t)(n0 + row) * K + k0 + sg * 8, Blf + idx * 8);
        }
        __syncthreads();
#pragma unroll
        for (int ks = 0; ks < 64; ks += 32) {
            const int s4 = ks >> 3;
            s16x8 af[4], bf[2];
#pragma unroll
            for (int i = 0; i < 4; i++) {
                int r = wr * 64 + i * 16 + cc;
                af[i] = *(const s16x8*)&Al[r][((s4 + qd) ^ (r & 7)) * 8];
            }
#pragma unroll
            for (int j = 0; j < 2; j++) {
                int r = wc * 32 + j * 16 + cc;
                bf[j] = *(const s16x8*)&Bl[r][((s4 + qd) ^ (r & 7)) * 8];
            }
#pragma unroll
            for (int i = 0; i < 4; i++)
#pragma unroll
                for (int j = 0; j < 2; j++)
                    acc[i][j] = MFMA_BF16(af[i], bf[j], acc[i][j]);
        }
        __syncthreads();
    }
#pragma unroll
    for (int i = 0; i < 4; i++)
#pragma unroll
        for (int j = 0; j < 2; j++)
#pragma unroll
            for (int r = 0; r < 4; r++) {
                int row = m0 + wr * 64 + i * 16 + qd * 4 + r;
                int col = n0 + wc * 32 + j * 16 + cc;
                C[(size_t)row * NN + col] = acc[i][j][r] + bias[col];
            }
}

// ---------------------------------------------------------------------------
extern "C" void kernel_launch(void* const* d_in, const int* in_sizes, int n_in,
                              void* d_out, int out_size, void* d_ws, size_t ws_size,
                              hipStream_t stream) {
    const float* x      = (const float*)d_in[0];
    const float* w_qkv  = (const float*)d_in[1];
    const float* w_proj = (const float*)d_in[2];
    const float* b_proj = (const float*)d_in[3];
    const int*   mask   = (const int*)d_in[4];
    float* out = (float*)d_out;

    // workspace layout (bf16 elements), ~72 MB
    unsigned short* ws     = (unsigned short*)d_ws;
    unsigned short* xb     = ws;                                  // 4096*1024
    unsigned short* wqkvb  = xb     + (size_t)4096 * 1024;        // 3072*1024
    unsigned short* wprojb = wqkvb  + (size_t)3072 * 1024;        // 1024*1024
    unsigned short* qkv    = wprojb + (size_t)1024 * 1024;        // 4096*3072
    unsigned short* Qm     = qkv    + (size_t)4096 * 3072;        // 32*2048*64
    unsigned short* Km     = Qm     + (size_t)32 * 2048 * 64;
    unsigned short* Vtm    = Km     + (size_t)32 * 2048 * 64;
    unsigned short* attno  = Vtm    + (size_t)32 * 2048 * 64;     // 4096*1024
    float*          fbias  = (float*)(attno + (size_t)4096 * 1024); // 2*2048 f32

    // converts + mask bias, one launch
    prep<<<8208, 256, 0, stream>>>(x, w_qkv, w_proj, mask, xb, wqkvb, wprojb, fbias);
    // qkv = x @ w_qkv^T   [4096, 3072]
    gemm_bt<<<dim3(24, 32), 256, 0, stream>>>(xb, wqkvb, qkv, 4096, 3072, 1024);
    // RoPE + scatter to Q/K [B,H,N,D] and Vt [B,H,D,N]  (dense 16B stores)
    rope_scatter<<<dim3(32, 16, 2), 256, 0, stream>>>(qkv, Qm, Km, Vtm);
    // attention: 128-row Q tiles, double-buffered staging
    flash_attn<<<dim3(16, 16, 2), 256, 0, stream>>>(Qm, Km, Vtm, fbias, attno);
    // out = attn_out @ w_proj^T + b_proj
    gemm_proj<<<dim3(16, 32), 256, 0, stream>>>(attno, wprojb, out, b_proj);
}